// Round 6
// baseline (227.311 us; speedup 1.0000x reference)
//
#include <hip/hip_runtime.h>
#include <hip/hip_bf16.h>
#include <math.h>

// Problem constants
#define BATCH   2
#define SEQ     2048
#define NHEAD   16
#define HDIM    64
#define NEMBD   1024
#define C3      (3*NEMBD)
#define MROWS   (BATCH*SEQ)   // 4096

typedef short bf16x8 __attribute__((ext_vector_type(8)));
typedef float f32x4  __attribute__((ext_vector_type(4)));

static __device__ __forceinline__ short f2bf(float x) {
    union { __hip_bfloat16 h; short s; } u;
    u.h = __float2bfloat16(x);
    return u.s;
}

static __device__ __forceinline__ void stc(float* p, float v) { *p = v; }
static __device__ __forceinline__ void stc(short* p, float v) { *p = f2bf(v); }

// async global->LDS, 16B per lane. LDS dest = wave-uniform base + lane*16.
static __device__ __forceinline__ void gl_lds16(const short* g, short* lds_base) {
    __builtin_amdgcn_global_load_lds(
        (const __attribute__((address_space(1))) unsigned int*)g,
        (__attribute__((address_space(3))) unsigned int*)lds_base,
        16, 0, 0);
}

// ---------------------------------------------------------------------------
// Elementwise fp32 -> bf16 convert (8 elems/thread).
// ---------------------------------------------------------------------------
__global__ __launch_bounds__(256) void conv_x(const float* __restrict__ in,
                                              short* __restrict__ out, int n) {
    const int i = (blockIdx.x * 256 + threadIdx.x) * 8;
    if (i >= n) return;
    float4 a = *(const float4*)(in + i);
    float4 b = *(const float4*)(in + i + 4);
    bf16x8 o;
    o[0] = f2bf(a.x); o[1] = f2bf(a.y); o[2] = f2bf(a.z); o[3] = f2bf(a.w);
    o[4] = f2bf(b.x); o[5] = f2bf(b.y); o[6] = f2bf(b.z); o[7] = f2bf(b.w);
    *(bf16x8*)(out + i) = o;
}

// ---------------------------------------------------------------------------
// Weight transpose + convert: in [K,N] fp32 row-major -> out [N,K] bf16.
// ---------------------------------------------------------------------------
__global__ __launch_bounds__(256) void conv_wt(const float* __restrict__ in,
                                               short* __restrict__ out,
                                               int K, int N) {
    __shared__ short tile[64][66];
    const int kt = blockIdx.y * 64, nt = blockIdx.x * 64;
    const int r  = threadIdx.x / 4;
    const int c0 = (threadIdx.x % 4) * 16;

    const float* src = in + (size_t)(kt + r) * N + nt + c0;
#pragma unroll
    for (int c = 0; c < 16; c += 4) {
        float4 v = *(const float4*)(src + c);
        tile[r][c0 + c + 0] = f2bf(v.x);
        tile[r][c0 + c + 1] = f2bf(v.y);
        tile[r][c0 + c + 2] = f2bf(v.z);
        tile[r][c0 + c + 3] = f2bf(v.w);
    }
    __syncthreads();

    const int nr  = threadIdx.x / 4;
    const int k0c = (threadIdx.x % 4) * 16;
    bf16x8 o0, o1;
#pragma unroll
    for (int k = 0; k < 8; ++k) o0[k] = tile[k0c + k][nr];
#pragma unroll
    for (int k = 0; k < 8; ++k) o1[k] = tile[k0c + 8 + k][nr];
    short* dst = out + (size_t)(nt + nr) * K + kt + k0c;
    *(bf16x8*)dst       = o0;
    *(bf16x8*)(dst + 8) = o1;
}

// ---------------------------------------------------------------------------
// bf16 MFMA GEMM (m97 structure): C = A @ B, A [M,K], BT [N,K] bf16.
// ---------------------------------------------------------------------------
template <typename OT>
__global__ __launch_bounds__(256) void gemm_bt(const short* __restrict__ A,
                                               const short* __restrict__ BT,
                                               OT* __restrict__ C,
                                               int M, int N, int K) {
    __shared__ short As[128 * 32];
    __shared__ short Bs[128 * 32];

    const int tid  = threadIdx.x;
    const int wave = tid >> 6;
    const int lane = tid & 63;
    const int quad = lane >> 4;
    const int col  = lane & 15;
    const int m0 = blockIdx.y * 128;
    const int n0 = blockIdx.x * 128;
    const int mq = (wave >> 1) * 64;
    const int nq = (wave & 1) * 64;

    f32x4 acc[4][4] = {};

    const int cA  = wave * 64 + lane;
    const int cA1 = cA + 256;

    for (int k0 = 0; k0 < K; k0 += 32) {
        if (k0) __syncthreads();
        gl_lds16(A + (size_t)(m0 + (cA  >> 2)) * K + k0 + (cA  & 3) * 8,
                 &As[wave * 512]);
        gl_lds16(A + (size_t)(m0 + (cA1 >> 2)) * K + k0 + (cA1 & 3) * 8,
                 &As[2048 + wave * 512]);
        gl_lds16(BT + (size_t)(n0 + (cA  >> 2)) * K + k0 + (cA  & 3) * 8,
                 &Bs[wave * 512]);
        gl_lds16(BT + (size_t)(n0 + (cA1 >> 2)) * K + k0 + (cA1 & 3) * 8,
                 &Bs[2048 + wave * 512]);
        __syncthreads();

        bf16x8 af[4], bfr[4];
#pragma unroll
        for (int mt = 0; mt < 4; ++mt)
            af[mt] = *(const bf16x8*)&As[(mq + mt * 16 + col) * 32 + quad * 8];
#pragma unroll
        for (int nt = 0; nt < 4; ++nt)
            bfr[nt] = *(const bf16x8*)&Bs[(nq + nt * 16 + col) * 32 + quad * 8];
#pragma unroll
        for (int mt = 0; mt < 4; ++mt)
#pragma unroll
            for (int nt = 0; nt < 4; ++nt)
                acc[mt][nt] = __builtin_amdgcn_mfma_f32_16x16x32_bf16(
                    af[mt], bfr[nt], acc[mt][nt], 0, 0, 0);
    }

#pragma unroll
    for (int mt = 0; mt < 4; ++mt)
#pragma unroll
        for (int r = 0; r < 4; ++r) {
            const int row = m0 + mq + mt * 16 + quad * 4 + r;
            OT* cp = C + (size_t)row * N + n0 + nq + col;
#pragma unroll
            for (int nt = 0; nt < 4; ++nt)
                stc(cp + nt * 16, acc[mt][nt][r]);
        }
}

// ---------------------------------------------------------------------------
// V transpose: qkvb bf16 [B*T,3072] (v at 2048+h*64) -> vt [B*H][64][2048]
// ---------------------------------------------------------------------------
__global__ __launch_bounds__(256) void conv_vt(const short* __restrict__ qkvb,
                                               short* __restrict__ vt) {
    __shared__ short tile[64][66];
    const int b = blockIdx.z, h = blockIdx.y, t0 = blockIdx.x * 64;
    const int tt = threadIdx.x / 4;
    const int c0 = (threadIdx.x % 4) * 16;

    const short* src = qkvb + (size_t)(b * SEQ + t0 + tt) * C3 + 2 * NEMBD + h * HDIM + c0;
    bf16x8 v0 = *(const bf16x8*)src;
    bf16x8 v1 = *(const bf16x8*)(src + 8);
#pragma unroll
    for (int k = 0; k < 8; ++k) tile[tt][c0 + k]     = v0[k];
#pragma unroll
    for (int k = 0; k < 8; ++k) tile[tt][c0 + 8 + k] = v1[k];
    __syncthreads();

    const int d  = threadIdx.x / 4;
    const int tp = (threadIdx.x % 4) * 16;
    bf16x8 o0, o1;
#pragma unroll
    for (int k = 0; k < 8; ++k) o0[k] = tile[tp + k][d];
#pragma unroll
    for (int k = 0; k < 8; ++k) o1[k] = tile[tp + 8 + k][d];
    short* dst = vt + ((size_t)(b * NHEAD + h) * HDIM + d) * SEQ + t0 + tp;
    *(bf16x8*)dst       = o0;
    *(bf16x8*)(dst + 8) = o1;
}

// ---------------------------------------------------------------------------
// MFMA flash attention v3: ALiBi (+slope*(i-j)), causal, fixed-max softmax
//   p = exp2(qk*scale2 - slope2*j)
// Changes vs v2 (R5):
//  * 1D grid, X is the SLOW index, descending -> all heaviest blocks (X=31,
//    every h,b) dispatch first; trivial (Tcut-truncated) blocks fill the tail.
//  * K double-buffered in LDS (16 KB, shared by 4 waves); V-fragments read
//    directly from linear vt (global/L2) -> LDS/block 40 -> ~25.6 KB
//    -> 6 blocks/CU resident.
//  * P row stride 72 shorts (144 B, 16B-aligned): scatter writes 8-way -> 4-way
//    bank conflicts; b128 reads stay balanced.
// ---------------------------------------------------------------------------
__global__ __launch_bounds__(256) void attn_mfma(const short* __restrict__ qkvb,
                                                 const short* __restrict__ vt,
                                                 short* __restrict__ out) {
    __shared__ short Ks[2][2][2048];     // [buf][lo/hi dims][64 keys * 32 shorts] 16 KB
    __shared__ short P_lds[4][16 * 72];  // per-wave, stride 72 -> 9.2 KB

    const int tid  = threadIdx.x;
    const int wave = tid >> 6;
    const int lane = tid & 63;
    const int quad = lane >> 4;
    const int col  = lane & 15;

    // 1D decode: X slow & descending (heavy first), then h, b
    const int w  = blockIdx.x;
    const int X  = 31 - (w >> 5);
    const int hb = w & 31;
    const int h  = hb >> 1;
    const int b  = hb & 1;
    const int q0 = X * 64 + wave * 16;

    const float LOG2E  = 1.4426950408889634f;
    const float scale2 = 0.125f * LOG2E;
    const float slope2 = exp2f(-0.5f * (float)(h + 1)) * LOG2E;

    // tile count: causal needs X+1; ALiBi cut: slope2*j <= 56 relevant
    const int Tneed = X + 1;
    const int Tcut  = ((int)(56.0f / slope2) >> 6) + 1;
    const int T     = Tneed < Tcut ? Tneed : Tcut;
    const bool masked_last = (T == Tneed);

    const short* kb  = qkvb + (size_t)(b * SEQ) * C3 + NEMBD + h * HDIM;
    const short* vtb = vt + (size_t)(b * NHEAD + h) * HDIM * SEQ;

    // Q A-fragments: rows q0+col, dims quad*8 (+0 / +32)
    const short* qbase = qkvb + (size_t)(b * SEQ + q0 + col) * C3 + h * HDIM;
    const bf16x8 qa0 = *(const bf16x8*)(qbase + quad * 8);
    const bf16x8 qa1 = *(const bf16x8*)(qbase + 32 + quad * 8);

    f32x4 O0 = {0,0,0,0}, O1 = {0,0,0,0}, O2 = {0,0,0,0}, O3 = {0,0,0,0};
    float lsum[4] = {0.f, 0.f, 0.f, 0.f};
    short* P = P_lds[wave];

    // stage K tile t: 256 threads x 2 chunks of 16B; chunk c=tid: row c>>2,
    // 8-group (c&3)*8; LDS linear offset c*8 shorts = wave*512 + lane*16B.
#define STAGE(t_, buf_) do {                                                   \
        const int jj = (t_) * 64;                                              \
        const int row = tid >> 2, g8 = (tid & 3) * 8;                          \
        gl_lds16(kb + (size_t)(jj + row) * C3 + g8,      &Ks[buf_][0][wave * 512]); \
        gl_lds16(kb + (size_t)(jj + row) * C3 + 32 + g8, &Ks[buf_][1][wave * 512]); \
    } while (0)

    STAGE(0, 0);

    for (int t = 0; t < T; ++t) {
        const int buf = t & 1;
        __syncthreads();            // drains vmcnt -> buf ready; prev reads done
        if (t + 1 < T) STAGE(t + 1, buf ^ 1);

        const int j0 = t * 64;

        // V B-fragments straight from global (linear vt, L2-hot):
        // dim c*16+col, keys j0+quad*8 (lo) / +32 (hi)
        bf16x8 vf[8];
#pragma unroll
        for (int c = 0; c < 4; ++c) {
            const short* vr = vtb + (size_t)(c * 16 + col) * SEQ + j0 + quad * 8;
            vf[2 * c]     = *(const bf16x8*)vr;
            vf[2 * c + 1] = *(const bf16x8*)(vr + 32);
        }

        // S = Q @ K^T from LDS K
        f32x4 S[4];
#pragma unroll
        for (int g = 0; g < 4; ++g) {
            bf16x8 k0 = *(const bf16x8*)&Ks[buf][0][(g * 16 + col) * 32 + quad * 8];
            bf16x8 k1 = *(const bf16x8*)&Ks[buf][1][(g * 16 + col) * 32 + quad * 8];
            f32x4 s = {0, 0, 0, 0};
            s = __builtin_amdgcn_mfma_f32_16x16x32_bf16(qa0, k0, s, 0, 0, 0);
            s = __builtin_amdgcn_mfma_f32_16x16x32_bf16(qa1, k1, s, 0, 0, 0);
            S[g] = s;
        }

        // softmax weights p = exp2(S*scale2 - slope2*j)
        const float cbase = -slope2 * (float)(j0 + col);
        const float d16   = -slope2 * 16.0f;
        float p[4][4];
        if (masked_last && t == T - 1) {
#pragma unroll
            for (int g = 0; g < 4; ++g) {
                const float cg = cbase + d16 * (float)g;
                const int   jg = j0 + g * 16 + col;
#pragma unroll
                for (int r = 0; r < 4; ++r) {
                    const int i = q0 + quad * 4 + r;
                    p[g][r] = (jg <= i) ? exp2f(S[g][r] * scale2 + cg) : 0.f;
                }
            }
        } else {
#pragma unroll
            for (int g = 0; g < 4; ++g) {
                const float cg = cbase + d16 * (float)g;
#pragma unroll
                for (int r = 0; r < 4; ++r)
                    p[g][r] = exp2f(S[g][r] * scale2 + cg);
            }
        }
#pragma unroll
        for (int r = 0; r < 4; ++r)
            lsum[r] += (p[0][r] + p[1][r]) + (p[2][r] + p[3][r]);

        // P (C-layout) -> LDS [q][k], row stride 72 -> A-layout fragments
#pragma unroll
        for (int g = 0; g < 4; ++g)
#pragma unroll
            for (int r = 0; r < 4; ++r)
                P[(quad * 4 + r) * 72 + g * 16 + col] = f2bf(p[g][r]);
        __asm__ volatile("s_waitcnt lgkmcnt(0)" ::: "memory");
        bf16x8 pa0 = *(bf16x8*)&P[col * 72 + quad * 8];
        bf16x8 pa1 = *(bf16x8*)&P[col * 72 + 32 + quad * 8];
        __asm__ volatile("" ::: "memory");

        // O += P @ V
        O0 = __builtin_amdgcn_mfma_f32_16x16x32_bf16(pa0, vf[0], O0, 0, 0, 0);
        O0 = __builtin_amdgcn_mfma_f32_16x16x32_bf16(pa1, vf[1], O0, 0, 0, 0);
        O1 = __builtin_amdgcn_mfma_f32_16x16x32_bf16(pa0, vf[2], O1, 0, 0, 0);
        O1 = __builtin_amdgcn_mfma_f32_16x16x32_bf16(pa1, vf[3], O1, 0, 0, 0);
        O2 = __builtin_amdgcn_mfma_f32_16x16x32_bf16(pa0, vf[4], O2, 0, 0, 0);
        O2 = __builtin_amdgcn_mfma_f32_16x16x32_bf16(pa1, vf[5], O2, 0, 0, 0);
        O3 = __builtin_amdgcn_mfma_f32_16x16x32_bf16(pa0, vf[6], O3, 0, 0, 0);
        O3 = __builtin_amdgcn_mfma_f32_16x16x32_bf16(pa1, vf[7], O3, 0, 0, 0);
    }
#undef STAGE

    // final l reduction across the 16 key-columns
#pragma unroll
    for (int off = 1; off < 16; off <<= 1)
#pragma unroll
        for (int r = 0; r < 4; ++r)
            lsum[r] += __shfl_xor(lsum[r], off);

#pragma unroll
    for (int r = 0; r < 4; ++r) {
        const float inv = 1.f / lsum[r];
        const int row = q0 + quad * 4 + r;
        short* op = out + (size_t)(b * SEQ + row) * NEMBD + h * HDIM;
        op[col]      = f2bf(O0[r] * inv);
        op[16 + col] = f2bf(O1[r] * inv);
        op[32 + col] = f2bf(O2[r] * inv);
        op[48 + col] = f2bf(O3[r] * inv);
    }
}

// ---------------------------------------------------------------------------
extern "C" void kernel_launch(void* const* d_in, const int* in_sizes, int n_in,
                              void* d_out, int out_size, void* d_ws, size_t ws_size,
                              hipStream_t stream) {
    const float* x      = (const float*)d_in[0];
    const float* w_qkv  = (const float*)d_in[1];
    const float* w_proj = (const float*)d_in[2];
    float* out = (float*)d_out;

    short* xb    = (short*)d_ws;
    short* wqt   = xb   + (size_t)MROWS * NEMBD;
    short* wpt   = wqt  + (size_t)C3 * NEMBD;
    short* qkvb  = wpt  + (size_t)NEMBD * NEMBD;
    short* attnb = qkvb + (size_t)MROWS * C3;
    short* vt = (short*)d_out;   // free until proj GEMM writes d_out

    conv_x<<<dim3(MROWS * NEMBD / (256 * 8)), 256, 0, stream>>>(x, xb, MROWS * NEMBD);
    conv_wt<<<dim3(C3 / 64, NEMBD / 64), 256, 0, stream>>>(w_qkv, wqt, NEMBD, C3);
    conv_wt<<<dim3(NEMBD / 64, NEMBD / 64), 256, 0, stream>>>(w_proj, wpt, NEMBD, NEMBD);
    gemm_bt<short><<<dim3(C3 / 128, MROWS / 128), 256, 0, stream>>>(
        xb, wqt, qkvb, MROWS, C3, NEMBD);
    conv_vt<<<dim3(SEQ / 64, NHEAD, BATCH), 256, 0, stream>>>(qkvb, vt);
    attn_mfma<<<dim3(32 * NHEAD * BATCH), 256, 0, stream>>>(qkvb, vt, attnb);
    gemm_bt<float><<<dim3(NEMBD / 128, MROWS / 128), 256, 0, stream>>>(
        attnb, wpt, out, MROWS, NEMBD, NEMBD);
}

// Round 7
// 218.246 us; speedup vs baseline: 1.0415x; 1.0415x over previous
//
#include <hip/hip_runtime.h>
#include <hip/hip_bf16.h>
#include <math.h>

// Problem constants
#define BATCH   2
#define SEQ     2048
#define NHEAD   16
#define HDIM    64
#define NEMBD   1024
#define C3      (3*NEMBD)
#define MROWS   (BATCH*SEQ)   // 4096

typedef short bf16x8 __attribute__((ext_vector_type(8)));
typedef short bf16x4 __attribute__((ext_vector_type(4)));
typedef float f32x4  __attribute__((ext_vector_type(4)));

static __device__ __forceinline__ short f2bf(float x) {
    union { __hip_bfloat16 h; short s; } u;
    u.h = __float2bfloat16(x);
    return u.s;
}

static __device__ __forceinline__ unsigned pack2(float a, float b) {
    return (unsigned)(unsigned short)f2bf(a) | ((unsigned)(unsigned short)f2bf(b) << 16);
}

static __device__ __forceinline__ void stc(float* p, float v) { *p = v; }
static __device__ __forceinline__ void stc(short* p, float v) { *p = f2bf(v); }

// async global->LDS, 16B per lane. LDS dest = wave-uniform base + lane*16.
static __device__ __forceinline__ void gl_lds16(const short* g, short* lds_base) {
    __builtin_amdgcn_global_load_lds(
        (const __attribute__((address_space(1))) unsigned int*)g,
        (__attribute__((address_space(3))) unsigned int*)lds_base,
        16, 0, 0);
}

// ---------------------------------------------------------------------------
// Elementwise fp32 -> bf16 convert (8 elems/thread).
// ---------------------------------------------------------------------------
__global__ __launch_bounds__(256) void conv_x(const float* __restrict__ in,
                                              short* __restrict__ out, int n) {
    const int i = (blockIdx.x * 256 + threadIdx.x) * 8;
    if (i >= n) return;
    float4 a = *(const float4*)(in + i);
    float4 b = *(const float4*)(in + i + 4);
    bf16x8 o;
    o[0] = f2bf(a.x); o[1] = f2bf(a.y); o[2] = f2bf(a.z); o[3] = f2bf(a.w);
    o[4] = f2bf(b.x); o[5] = f2bf(b.y); o[6] = f2bf(b.z); o[7] = f2bf(b.w);
    *(bf16x8*)(out + i) = o;
}

// ---------------------------------------------------------------------------
// Weight transpose + convert: in [K,N] fp32 row-major -> out [N,K] bf16.
// ---------------------------------------------------------------------------
__global__ __launch_bounds__(256) void conv_wt(const float* __restrict__ in,
                                               short* __restrict__ out,
                                               int K, int N) {
    __shared__ short tile[64][66];
    const int kt = blockIdx.y * 64, nt = blockIdx.x * 64;
    const int r  = threadIdx.x / 4;
    const int c0 = (threadIdx.x % 4) * 16;

    const float* src = in + (size_t)(kt + r) * N + nt + c0;
#pragma unroll
    for (int c = 0; c < 16; c += 4) {
        float4 v = *(const float4*)(src + c);
        tile[r][c0 + c + 0] = f2bf(v.x);
        tile[r][c0 + c + 1] = f2bf(v.y);
        tile[r][c0 + c + 2] = f2bf(v.z);
        tile[r][c0 + c + 3] = f2bf(v.w);
    }
    __syncthreads();

    const int nr  = threadIdx.x / 4;
    const int k0c = (threadIdx.x % 4) * 16;
    bf16x8 o0, o1;
#pragma unroll
    for (int k = 0; k < 8; ++k) o0[k] = tile[k0c + k][nr];
#pragma unroll
    for (int k = 0; k < 8; ++k) o1[k] = tile[k0c + 8 + k][nr];
    short* dst = out + (size_t)(nt + nr) * K + kt + k0c;
    *(bf16x8*)dst       = o0;
    *(bf16x8*)(dst + 8) = o1;
}

// ---------------------------------------------------------------------------
// bf16 MFMA GEMM (m97 structure): C = A @ B, A [M,K], BT [N,K] bf16.
// ---------------------------------------------------------------------------
template <typename OT>
__global__ __launch_bounds__(256) void gemm_bt(const short* __restrict__ A,
                                               const short* __restrict__ BT,
                                               OT* __restrict__ C,
                                               int M, int N, int K) {
    __shared__ short As[128 * 32];
    __shared__ short Bs[128 * 32];

    const int tid  = threadIdx.x;
    const int wave = tid >> 6;
    const int lane = tid & 63;
    const int quad = lane >> 4;
    const int col  = lane & 15;
    const int m0 = blockIdx.y * 128;
    const int n0 = blockIdx.x * 128;
    const int mq = (wave >> 1) * 64;
    const int nq = (wave & 1) * 64;

    f32x4 acc[4][4] = {};

    const int cA  = wave * 64 + lane;
    const int cA1 = cA + 256;

    for (int k0 = 0; k0 < K; k0 += 32) {
        if (k0) __syncthreads();
        gl_lds16(A + (size_t)(m0 + (cA  >> 2)) * K + k0 + (cA  & 3) * 8,
                 &As[wave * 512]);
        gl_lds16(A + (size_t)(m0 + (cA1 >> 2)) * K + k0 + (cA1 & 3) * 8,
                 &As[2048 + wave * 512]);
        gl_lds16(BT + (size_t)(n0 + (cA  >> 2)) * K + k0 + (cA  & 3) * 8,
                 &Bs[wave * 512]);
        gl_lds16(BT + (size_t)(n0 + (cA1 >> 2)) * K + k0 + (cA1 & 3) * 8,
                 &Bs[2048 + wave * 512]);
        __syncthreads();

        bf16x8 af[4], bfr[4];
#pragma unroll
        for (int mt = 0; mt < 4; ++mt)
            af[mt] = *(const bf16x8*)&As[(mq + mt * 16 + col) * 32 + quad * 8];
#pragma unroll
        for (int nt = 0; nt < 4; ++nt)
            bfr[nt] = *(const bf16x8*)&Bs[(nq + nt * 16 + col) * 32 + quad * 8];
#pragma unroll
        for (int mt = 0; mt < 4; ++mt)
#pragma unroll
            for (int nt = 0; nt < 4; ++nt)
                acc[mt][nt] = __builtin_amdgcn_mfma_f32_16x16x32_bf16(
                    af[mt], bfr[nt], acc[mt][nt], 0, 0, 0);
    }

#pragma unroll
    for (int mt = 0; mt < 4; ++mt)
#pragma unroll
        for (int r = 0; r < 4; ++r) {
            const int row = m0 + mq + mt * 16 + quad * 4 + r;
            OT* cp = C + (size_t)row * N + n0 + nq + col;
#pragma unroll
            for (int nt = 0; nt < 4; ++nt)
                stc(cp + nt * 16, acc[mt][nt][r]);
        }
}

// ---------------------------------------------------------------------------
// V transpose: qkvb bf16 [B*T,3072] (v at 2048+h*64) -> vt [B*H][64][2048]
// ---------------------------------------------------------------------------
__global__ __launch_bounds__(256) void conv_vt(const short* __restrict__ qkvb,
                                               short* __restrict__ vt) {
    __shared__ short tile[64][66];
    const int b = blockIdx.z, h = blockIdx.y, t0 = blockIdx.x * 64;
    const int tt = threadIdx.x / 4;
    const int c0 = (threadIdx.x % 4) * 16;

    const short* src = qkvb + (size_t)(b * SEQ + t0 + tt) * C3 + 2 * NEMBD + h * HDIM + c0;
    bf16x8 v0 = *(const bf16x8*)src;
    bf16x8 v1 = *(const bf16x8*)(src + 8);
#pragma unroll
    for (int k = 0; k < 8; ++k) tile[tt][c0 + k]     = v0[k];
#pragma unroll
    for (int k = 0; k < 8; ++k) tile[tt][c0 + 8 + k] = v1[k];
    __syncthreads();

    const int d  = threadIdx.x / 4;
    const int tp = (threadIdx.x % 4) * 16;
    bf16x8 o0, o1;
#pragma unroll
    for (int k = 0; k < 8; ++k) o0[k] = tile[tp + k][d];
#pragma unroll
    for (int k = 0; k < 8; ++k) o1[k] = tile[tp + 8 + k][d];
    short* dst = vt + ((size_t)(b * NHEAD + h) * HDIM + d) * SEQ + t0 + tp;
    *(bf16x8*)dst       = o0;
    *(bf16x8*)(dst + 8) = o1;
}

// ---------------------------------------------------------------------------
// MFMA flash attention v4: ALiBi (+slope*(i-j)), causal, fixed-max softmax
//   p = exp2(qk*scale2 - slope2*j)
// S^T orientation: S^T = K@Q^T (A=K-frag, B=Q-frag; layouts lane-identical),
// so C-layout has q=col, key=g*16+quad*4+r. PV: O^T = V^T@P^T (A=V^T-frag,
// B=P^T read from LDS at the SAME addresses as v3). Benefits: paired b32 P
// writes, single lsum + 2 shuffles, vectorized 8B epilogue stores.
// 32 queries/wave (2 subtiles share each staged K/V tile), 4 waves = 128 q.
// K+V double-buffered in LDS (R5-style coalesced staging; R6's direct-global
// V reads were request-rate bound - 64 lines/instr).
// Work queue: heavy-first items popped via device atomic -> no dispatch-order
// tail. 512 items (16 X x 32 hb), 512 blocks.
// ---------------------------------------------------------------------------
__global__ __launch_bounds__(256) void attn_mfma(const short* __restrict__ qkvb,
                                                 const short* __restrict__ vt,
                                                 short* __restrict__ out,
                                                 int* __restrict__ qcnt) {
    // [buf][region][64 rows * 32 shorts]; regions: 0=Klo 1=Khi 2=Vlo 3=Vhi
    __shared__ short KV[2][4][2048];     // 32 KB
    __shared__ short P_lds[4][16 * 72];  // per-wave P^T as [q][key], 9.2 KB
    __shared__ int item_s;

    const int tid  = threadIdx.x;
    const int wave = tid >> 6;
    const int lane = tid & 63;
    const int quad = lane >> 4;
    const int col  = lane & 15;

    const float LOG2E  = 1.4426950408889634f;
    const float scale2 = 0.125f * LOG2E;
    short* P = P_lds[wave];

#define STAGE(t_, buf_) do {                                                   \
        const int jj = (t_) * 64;                                              \
        const int row = tid >> 2, g8 = (tid & 3) * 8;                          \
        gl_lds16(kb  + (size_t)(jj + row) * C3 + g8,      &KV[buf_][0][wave * 512]); \
        gl_lds16(kb  + (size_t)(jj + row) * C3 + 32 + g8, &KV[buf_][1][wave * 512]); \
        gl_lds16(vtb + (size_t)row * SEQ + jj + g8,       &KV[buf_][2][wave * 512]); \
        gl_lds16(vtb + (size_t)row * SEQ + jj + 32 + g8,  &KV[buf_][3][wave * 512]); \
    } while (0)

    for (;;) {
        __syncthreads();                       // protect item_s + LDS reuse
        if (tid == 0) item_s = atomicAdd(qcnt, 1);
        __syncthreads();
        const int it = item_s;
        if (it >= 16 * 32) return;

        // decode: X slow & descending (heavy first), then h, b
        const int X  = 15 - (it >> 5);
        const int hb = it & 31;
        const int h  = hb >> 1;
        const int b  = hb & 1;
        const int q0w = X * 128 + wave * 32;   // this wave's 32-query base

        const float slope2 = exp2f(-0.5f * (float)(h + 1)) * LOG2E;
        const int Tneed = 2 * X + 2;
        const int Tcut  = ((int)(56.0f / slope2) >> 6) + 1;  // ALiBi truncation
        const int T     = Tneed < Tcut ? Tneed : Tcut;

        const short* kb  = qkvb + (size_t)(b * SEQ) * C3 + NEMBD + h * HDIM;
        const short* vtb = vt + (size_t)(b * NHEAD + h) * HDIM * SEQ;

        // Q B-fragments for 2 subtiles: B[d=quad*8+j][q=col]
        bf16x8 qa[2][2];
#pragma unroll
        for (int u = 0; u < 2; ++u) {
            const short* qb = qkvb + (size_t)(b * SEQ + q0w + u * 16 + col) * C3 + h * HDIM;
            qa[u][0] = *(const bf16x8*)(qb + quad * 8);
            qa[u][1] = *(const bf16x8*)(qb + 32 + quad * 8);
        }

        f32x4 O[2][4] = {};              // O^T[d=c*16+quad*4+r][q=col]
        float lsum[2] = {0.f, 0.f};

        STAGE(0, 0);

        for (int t = 0; t < T; ++t) {
            const int buf = t & 1;
            __syncthreads();             // buf ready (vmcnt drained); prev reads done
            if (t + 1 < T) STAGE(t + 1, buf ^ 1);

            const int j0 = t * 64;

            // K A-fragments: A[key=g*16+col][d=quad*8+j]
            bf16x8 kf0[4], kf1[4];
#pragma unroll
            for (int g = 0; g < 4; ++g) {
                kf0[g] = *(const bf16x8*)&KV[buf][0][(g * 16 + col) * 32 + quad * 8];
                kf1[g] = *(const bf16x8*)&KV[buf][1][(g * 16 + col) * 32 + quad * 8];
            }

            // S^T = K @ Q^T for both q-subtiles
            f32x4 S[2][4];
#pragma unroll
            for (int u = 0; u < 2; ++u)
#pragma unroll
                for (int g = 0; g < 4; ++g) {
                    f32x4 s = {0, 0, 0, 0};
                    s = __builtin_amdgcn_mfma_f32_16x16x32_bf16(kf0[g], qa[u][0], s, 0, 0, 0);
                    s = __builtin_amdgcn_mfma_f32_16x16x32_bf16(kf1[g], qa[u][1], s, 0, 0, 0);
                    S[u][g] = s;
                }

            // V^T A-fragments: A[d=c*16+col][key=quad*8+j] (lo/hi key halves)
            bf16x8 vf0[4], vf1[4];
#pragma unroll
            for (int c = 0; c < 4; ++c) {
                vf0[c] = *(const bf16x8*)&KV[buf][2][(c * 16 + col) * 32 + quad * 8];
                vf1[c] = *(const bf16x8*)&KV[buf][3][(c * 16 + col) * 32 + quad * 8];
            }

            const float kb_f = (float)(j0 + quad * 4);   // lane's key base

#pragma unroll
            for (int u = 0; u < 2; ++u) {
                // p = exp2(S*scale2 - slope2*key), key = j0+g*16+quad*4+r
                float p[4][4];
                if (j0 + 63 >= q0w + u * 16) {           // causal mask needed
                    const int q_i = q0w + u * 16 + col;
#pragma unroll
                    for (int g = 0; g < 4; ++g)
#pragma unroll
                        for (int r = 0; r < 4; ++r) {
                            const int key = j0 + g * 16 + quad * 4 + r;
                            p[g][r] = (key <= q_i)
                                ? exp2f(S[u][g][r] * scale2 - slope2 * (float)key)
                                : 0.f;
                        }
                } else {
#pragma unroll
                    for (int g = 0; g < 4; ++g)
#pragma unroll
                        for (int r = 0; r < 4; ++r)
                            p[g][r] = exp2f(S[u][g][r] * scale2
                                            - slope2 * (kb_f + (float)(g * 16 + r)));
                }
#pragma unroll
                for (int r = 0; r < 4; ++r)
                    lsum[u] += (p[0][r] + p[1][r]) + (p[2][r] + p[3][r]);

                // P^T -> LDS as [q=col][key], paired b32 writes
#pragma unroll
                for (int g = 0; g < 4; ++g) {
                    *(unsigned*)&P[col * 72 + g * 16 + quad * 4]     = pack2(p[g][0], p[g][1]);
                    *(unsigned*)&P[col * 72 + g * 16 + quad * 4 + 2] = pack2(p[g][2], p[g][3]);
                }
                __asm__ volatile("s_waitcnt lgkmcnt(0)" ::: "memory");
                // B-fragments: B[key=half*32+quad*8+j][q=col]
                bf16x8 pb0 = *(bf16x8*)&P[col * 72 + quad * 8];
                bf16x8 pb1 = *(bf16x8*)&P[col * 72 + 32 + quad * 8];
                __asm__ volatile("" ::: "memory");       // reads before next writes

                // O^T += V^T @ P^T
#pragma unroll
                for (int c = 0; c < 4; ++c) {
                    O[u][c] = __builtin_amdgcn_mfma_f32_16x16x32_bf16(vf0[c], pb0, O[u][c], 0, 0, 0);
                    O[u][c] = __builtin_amdgcn_mfma_f32_16x16x32_bf16(vf1[c], pb1, O[u][c], 0, 0, 0);
                }
            }
        }

        // epilogue: lane holds O^T[d=c*16+quad*4+r][q=col] -> row q, 4x 8B stores
#pragma unroll
        for (int u = 0; u < 2; ++u) {
            float l = lsum[u];
            l += __shfl_xor(l, 16);
            l += __shfl_xor(l, 32);
            const float inv = 1.f / l;
            short* op = out + (size_t)(b * SEQ + q0w + u * 16 + col) * NEMBD + h * HDIM;
#pragma unroll
            for (int c = 0; c < 4; ++c) {
                bf16x4 v;
                v[0] = f2bf(O[u][c][0] * inv);
                v[1] = f2bf(O[u][c][1] * inv);
                v[2] = f2bf(O[u][c][2] * inv);
                v[3] = f2bf(O[u][c][3] * inv);
                *(bf16x4*)(op + c * 16 + quad * 4) = v;
            }
        }
    }
#undef STAGE
}

// ---------------------------------------------------------------------------
extern "C" void kernel_launch(void* const* d_in, const int* in_sizes, int n_in,
                              void* d_out, int out_size, void* d_ws, size_t ws_size,
                              hipStream_t stream) {
    const float* x      = (const float*)d_in[0];
    const float* w_qkv  = (const float*)d_in[1];
    const float* w_proj = (const float*)d_in[2];
    float* out = (float*)d_out;

    short* xb    = (short*)d_ws;
    short* wqt   = xb   + (size_t)MROWS * NEMBD;
    short* wpt   = wqt  + (size_t)C3 * NEMBD;
    short* qkvb  = wpt  + (size_t)NEMBD * NEMBD;
    short* attnb = qkvb + (size_t)MROWS * C3;
    int*   qcnt  = (int*)(attnb + (size_t)MROWS * NEMBD);  // work-queue counter
    short* vt = (short*)d_out;   // free until proj GEMM writes d_out

    conv_x<<<dim3(MROWS * NEMBD / (256 * 8)), 256, 0, stream>>>(x, xb, MROWS * NEMBD);
    conv_wt<<<dim3(C3 / 64, NEMBD / 64), 256, 0, stream>>>(w_qkv, wqt, NEMBD, C3);
    conv_wt<<<dim3(NEMBD / 64, NEMBD / 64), 256, 0, stream>>>(w_proj, wpt, NEMBD, NEMBD);
    gemm_bt<short><<<dim3(C3 / 128, MROWS / 128), 256, 0, stream>>>(
        xb, wqt, qkvb, MROWS, C3, NEMBD);
    conv_vt<<<dim3(SEQ / 64, NHEAD, BATCH), 256, 0, stream>>>(qkvb, vt);
    hipMemsetAsync(qcnt, 0, sizeof(int), stream);
    attn_mfma<<<dim3(512), 256, 0, stream>>>(qkvb, vt, attnb, qcnt);
    gemm_bt<float><<<dim3(NEMBD / 128, MROWS / 128), 256, 0, stream>>>(
        attnb, wpt, out, MROWS, NEMBD, NEMBD);
}